// Round 1
// baseline (1798.472 us; speedup 1.0000x reference)
//
#include <hip/hip_runtime.h>
#include <math.h>

constexpr int B = 4, N = 4096, D = 256;
constexpr int BN = B * N;
constexpr float EPS = 1e-5f;
constexpr float SCALE = 0.0625f; // D^-0.5 = 1/16

// LDS strides (floats). Chosen so b128 reads are <=2-way bank conflicts and
// every float4 access stays 16B-aligned (stride % 4 == 0).
constexpr int ASTR = 36;   // A tiles, rows read 4 apart: 4*36=144 ≡ 16 (mod 32 banks)
constexpr int BSTR = 72;   // B tiles
constexpr int QSTR = 36;
constexpr int KTSTR = 68;  // transposed K chunk [32][68]
constexpr int PSTR = 68;   // P tile, rows read 4 apart: 4*68=272 ≡ 16 (mod 32)
constexpr int VSTR = 72;

// ---------------- LayerNorm row statistics ----------------
__global__ __launch_bounds__(256) void ln_stats_kernel(
    const float* __restrict__ x, float* __restrict__ st) {
  const int row = blockIdx.x;
  const int t = threadIdx.x;
  const float v = x[(size_t)row * D + t];
  float s = v, ss = v * v;
#pragma unroll
  for (int o = 32; o > 0; o >>= 1) {
    s += __shfl_down(s, o);
    ss += __shfl_down(ss, o);
  }
  __shared__ float red[8];
  if ((t & 63) == 0) {
    red[t >> 6] = s;
    red[(t >> 6) + 4] = ss;
  }
  __syncthreads();
  if (t == 0) {
    s = red[0] + red[1] + red[2] + red[3];
    ss = red[4] + red[5] + red[6] + red[7];
    const float mu = s * (1.0f / D);
    const float var = ss * (1.0f / D) - mu * mu;
    st[2 * row] = mu;
    st[2 * row + 1] = rsqrtf(var + EPS);
  }
}

// ---------------- fused LN + QKV GEMM + coord bias ----------------
// A = LN(x) [BN x 256], Bmat = w_qkv [256 x 768]. Tile 64x64, BK=32, 4x4 micro.
__global__ __launch_bounds__(256) void qkv_kernel(
    const float* __restrict__ x, const float* __restrict__ st,
    const float* __restrict__ g, const float* __restrict__ bta,
    const float* __restrict__ w, const float* __restrict__ coord,
    float* __restrict__ qb, float* __restrict__ kb, float* __restrict__ vb) {
  __shared__ float As[64 * ASTR];
  __shared__ float Bs[32 * BSTR];
  const int t = threadIdx.x;
  const int tr = t >> 4, tc = t & 15;
  const int r0 = blockIdx.x * 64;
  const int c0 = blockIdx.y * 64;  // within [0,768)
  float acc[4][4] = {};
  const int lr = t >> 3, lc = (t & 7) * 4;    // A load: 64x32
  const int br = t >> 4, bc4 = (t & 15) * 4;  // B load: 32x64

  const float mu0 = st[2 * (r0 + lr)], rg0 = st[2 * (r0 + lr) + 1];
  const float mu1 = st[2 * (r0 + lr + 32)], rg1 = st[2 * (r0 + lr + 32) + 1];

  for (int kc = 0; kc < D; kc += 32) {
    __syncthreads();
    {
      float4 xa = *(const float4*)&x[(size_t)(r0 + lr) * D + kc + lc];
      float4 xb = *(const float4*)&x[(size_t)(r0 + lr + 32) * D + kc + lc];
      const float4 gv = *(const float4*)&g[kc + lc];
      const float4 bv = *(const float4*)&bta[kc + lc];
      float4 a0, a1;
      a0.x = (xa.x - mu0) * rg0 * gv.x + bv.x;
      a0.y = (xa.y - mu0) * rg0 * gv.y + bv.y;
      a0.z = (xa.z - mu0) * rg0 * gv.z + bv.z;
      a0.w = (xa.w - mu0) * rg0 * gv.w + bv.w;
      a1.x = (xb.x - mu1) * rg1 * gv.x + bv.x;
      a1.y = (xb.y - mu1) * rg1 * gv.y + bv.y;
      a1.z = (xb.z - mu1) * rg1 * gv.z + bv.z;
      a1.w = (xb.w - mu1) * rg1 * gv.w + bv.w;
      *(float4*)&As[lr * ASTR + lc] = a0;
      *(float4*)&As[(lr + 32) * ASTR + lc] = a1;
      *(float4*)&Bs[br * BSTR + bc4] =
          *(const float4*)&w[(size_t)(kc + br) * 768 + c0 + bc4];
      *(float4*)&Bs[(br + 16) * BSTR + bc4] =
          *(const float4*)&w[(size_t)(kc + br + 16) * 768 + c0 + bc4];
    }
    __syncthreads();
#pragma unroll
    for (int kk = 0; kk < 32; kk += 4) {
      float ar[4][4];
#pragma unroll
      for (int i = 0; i < 4; ++i) {
        const float4 av = *(const float4*)&As[(tr * 4 + i) * ASTR + kk];
        ar[i][0] = av.x; ar[i][1] = av.y; ar[i][2] = av.z; ar[i][3] = av.w;
      }
#pragma unroll
      for (int dd = 0; dd < 4; ++dd) {
        const float4 bv = *(const float4*)&Bs[(kk + dd) * BSTR + tc * 4];
#pragma unroll
        for (int i = 0; i < 4; ++i) {
          acc[i][0] += ar[i][dd] * bv.x;
          acc[i][1] += ar[i][dd] * bv.y;
          acc[i][2] += ar[i][dd] * bv.z;
          acc[i][3] += ar[i][dd] * bv.w;
        }
      }
    }
  }
  const int region = c0 >> 8;  // 0:q 1:k 2:v (uniform per block)
  const int cr = (c0 & 255) + tc * 4;
  float* dst = region == 0 ? qb : (region == 1 ? kb : vb);
#pragma unroll
  for (int i = 0; i < 4; ++i) {
    const int row = r0 + tr * 4 + i;
    float4 r;
    r.x = acc[i][0]; r.y = acc[i][1]; r.z = acc[i][2]; r.w = acc[i][3];
    if (region < 2) {
      const float4 c = *(const float4*)&coord[(size_t)row * D + cr];
      r.x += c.x; r.y += c.y; r.z += c.z; r.w += c.w;
    }
    *(float4*)&dst[(size_t)row * D + cr] = r;
  }
}

// ---------------- flash attention ----------------
// One block per (batch, 64 query rows). KB=64 keys per tile. 256 threads,
// 4x4 micro for S, each thread owns O[4 rows][16 cols].
__global__ __launch_bounds__(256) void attn_kernel(
    const float* __restrict__ qg, const float* __restrict__ kg,
    const float* __restrict__ vg, float* __restrict__ og) {
  __shared__ float qs[64 * QSTR];
  __shared__ float kts[32 * KTSTR];  // transposed: [d][key]
  __shared__ float ps[64 * PSTR];
  __shared__ float vs[64 * VSTR];
  const int t = threadIdx.x;
  const int tr = t >> 4, tc = t & 15;
  const int b = blockIdx.y;
  const int q0 = blockIdx.x * 64;
  const float* qb = qg + (size_t)b * N * D;
  const float* kb = kg + (size_t)b * N * D;
  const float* vb = vg + (size_t)b * N * D;

  float m[4], l[4], o[4][16];
#pragma unroll
  for (int i = 0; i < 4; ++i) {
    m[i] = -INFINITY;
    l[i] = 0.f;
#pragma unroll
    for (int c = 0; c < 16; ++c) o[i][c] = 0.f;
  }

  const int lr = t >> 3, lc = (t & 7) * 4;   // 64x32 q/k chunk loads
  const int vr = t >> 4, vc = (t & 15) * 4;  // 64x64 v chunk loads

  for (int k0 = 0; k0 < N; k0 += 64) {
    // ---- S = Q K^T for this tile ----
    float s[4][4] = {};
    for (int dc = 0; dc < D; dc += 32) {
      __syncthreads();
      *(float4*)&qs[lr * QSTR + lc] =
          *(const float4*)&qb[(size_t)(q0 + lr) * D + dc + lc];
      *(float4*)&qs[(lr + 32) * QSTR + lc] =
          *(const float4*)&qb[(size_t)(q0 + lr + 32) * D + dc + lc];
      {
        const float4 k0v = *(const float4*)&kb[(size_t)(k0 + lr) * D + dc + lc];
        const float4 k1v = *(const float4*)&kb[(size_t)(k0 + lr + 32) * D + dc + lc];
        kts[(lc + 0) * KTSTR + lr] = k0v.x;
        kts[(lc + 1) * KTSTR + lr] = k0v.y;
        kts[(lc + 2) * KTSTR + lr] = k0v.z;
        kts[(lc + 3) * KTSTR + lr] = k0v.w;
        kts[(lc + 0) * KTSTR + lr + 32] = k1v.x;
        kts[(lc + 1) * KTSTR + lr + 32] = k1v.y;
        kts[(lc + 2) * KTSTR + lr + 32] = k1v.z;
        kts[(lc + 3) * KTSTR + lr + 32] = k1v.w;
      }
      __syncthreads();
#pragma unroll
      for (int kk = 0; kk < 32; kk += 4) {
        float ar[4][4];
#pragma unroll
        for (int i = 0; i < 4; ++i) {
          const float4 av = *(const float4*)&qs[(tr * 4 + i) * QSTR + kk];
          ar[i][0] = av.x; ar[i][1] = av.y; ar[i][2] = av.z; ar[i][3] = av.w;
        }
#pragma unroll
        for (int dd = 0; dd < 4; ++dd) {
          const float4 kv = *(const float4*)&kts[(kk + dd) * KTSTR + tc * 4];
#pragma unroll
          for (int i = 0; i < 4; ++i) {
            s[i][0] += ar[i][dd] * kv.x;
            s[i][1] += ar[i][dd] * kv.y;
            s[i][2] += ar[i][dd] * kv.z;
            s[i][3] += ar[i][dd] * kv.w;
          }
        }
      }
    }
    // ---- online softmax update ----
#pragma unroll
    for (int i = 0; i < 4; ++i) {
      s[i][0] *= SCALE; s[i][1] *= SCALE; s[i][2] *= SCALE; s[i][3] *= SCALE;
      float rm = fmaxf(fmaxf(s[i][0], s[i][1]), fmaxf(s[i][2], s[i][3]));
#pragma unroll
      for (int off = 1; off < 16; off <<= 1) rm = fmaxf(rm, __shfl_xor(rm, off));
      const float mn = fmaxf(m[i], rm);
      const float f = expf(m[i] - mn);
      float p0 = expf(s[i][0] - mn), p1 = expf(s[i][1] - mn);
      float p2 = expf(s[i][2] - mn), p3 = expf(s[i][3] - mn);
      float rs = p0 + p1 + p2 + p3;
#pragma unroll
      for (int off = 1; off < 16; off <<= 1) rs += __shfl_xor(rs, off);
      l[i] = l[i] * f + rs;
      m[i] = mn;
#pragma unroll
      for (int c = 0; c < 16; ++c) o[i][c] *= f;
      float4 pw; pw.x = p0; pw.y = p1; pw.z = p2; pw.w = p3;
      *(float4*)&ps[(tr * 4 + i) * PSTR + tc * 4] = pw;
    }
    // ---- O += P V ----
#pragma unroll 1
    for (int ch = 0; ch < 4; ++ch) {
      __syncthreads();
#pragma unroll
      for (int rr = 0; rr < 4; ++rr)
        *(float4*)&vs[(vr + rr * 16) * VSTR + vc] =
            *(const float4*)&vb[(size_t)(k0 + vr + rr * 16) * D + ch * 64 + vc];
      __syncthreads();
#pragma unroll 2
      for (int j = 0; j < 64; j += 4) {
        float pr[4][4];
#pragma unroll
        for (int i = 0; i < 4; ++i) {
          const float4 p4 = *(const float4*)&ps[(tr * 4 + i) * PSTR + j];
          pr[i][0] = p4.x; pr[i][1] = p4.y; pr[i][2] = p4.z; pr[i][3] = p4.w;
        }
#pragma unroll
        for (int jj = 0; jj < 4; ++jj) {
          const float4 vv = *(const float4*)&vs[(j + jj) * VSTR + tc * 4];
#pragma unroll
          for (int i = 0; i < 4; ++i) {
            o[i][ch * 4 + 0] += pr[i][jj] * vv.x;
            o[i][ch * 4 + 1] += pr[i][jj] * vv.y;
            o[i][ch * 4 + 2] += pr[i][jj] * vv.z;
            o[i][ch * 4 + 3] += pr[i][jj] * vv.w;
          }
        }
      }
    }
  }
  // ---- epilogue: O /= l ----
#pragma unroll
  for (int i = 0; i < 4; ++i) {
    const float inv = 1.0f / l[i];
    const size_t row = (size_t)b * N + q0 + tr * 4 + i;
#pragma unroll
    for (int ch = 0; ch < 4; ++ch) {
      float4 r;
      r.x = o[i][ch * 4 + 0] * inv;
      r.y = o[i][ch * 4 + 1] * inv;
      r.z = o[i][ch * 4 + 2] * inv;
      r.w = o[i][ch * 4 + 3] * inv;
      *(float4*)&og[row * D + ch * 64 + tc * 4] = r;
    }
  }
}

// ---------------- output projection + bias ----------------
__global__ __launch_bounds__(256) void proj_kernel(
    const float* __restrict__ a, const float* __restrict__ w,
    const float* __restrict__ bias, float* __restrict__ out) {
  __shared__ float As[64 * ASTR];
  __shared__ float Bs[32 * BSTR];
  const int t = threadIdx.x;
  const int tr = t >> 4, tc = t & 15;
  const int r0 = blockIdx.x * 64;
  const int c0 = blockIdx.y * 64;
  float acc[4][4] = {};
  const int lr = t >> 3, lc = (t & 7) * 4;
  const int br = t >> 4, bc4 = (t & 15) * 4;
  for (int kc = 0; kc < D; kc += 32) {
    __syncthreads();
    *(float4*)&As[lr * ASTR + lc] =
        *(const float4*)&a[(size_t)(r0 + lr) * D + kc + lc];
    *(float4*)&As[(lr + 32) * ASTR + lc] =
        *(const float4*)&a[(size_t)(r0 + lr + 32) * D + kc + lc];
    *(float4*)&Bs[br * BSTR + bc4] =
        *(const float4*)&w[(size_t)(kc + br) * D + c0 + bc4];
    *(float4*)&Bs[(br + 16) * BSTR + bc4] =
        *(const float4*)&w[(size_t)(kc + br + 16) * D + c0 + bc4];
    __syncthreads();
#pragma unroll
    for (int kk = 0; kk < 32; kk += 4) {
      float ar[4][4];
#pragma unroll
      for (int i = 0; i < 4; ++i) {
        const float4 av = *(const float4*)&As[(tr * 4 + i) * ASTR + kk];
        ar[i][0] = av.x; ar[i][1] = av.y; ar[i][2] = av.z; ar[i][3] = av.w;
      }
#pragma unroll
      for (int dd = 0; dd < 4; ++dd) {
        const float4 bv = *(const float4*)&Bs[(kk + dd) * BSTR + tc * 4];
#pragma unroll
        for (int i = 0; i < 4; ++i) {
          acc[i][0] += ar[i][dd] * bv.x;
          acc[i][1] += ar[i][dd] * bv.y;
          acc[i][2] += ar[i][dd] * bv.z;
          acc[i][3] += ar[i][dd] * bv.w;
        }
      }
    }
  }
  const int cg = c0 + tc * 4;
  const float4 bv = *(const float4*)&bias[cg];
#pragma unroll
  for (int i = 0; i < 4; ++i) {
    const int row = r0 + tr * 4 + i;
    float4 r;
    r.x = acc[i][0] + bv.x;
    r.y = acc[i][1] + bv.y;
    r.z = acc[i][2] + bv.z;
    r.w = acc[i][3] + bv.w;
    *(float4*)&out[(size_t)row * D + cg] = r;
  }
}

extern "C" void kernel_launch(void* const* d_in, const int* in_sizes, int n_in,
                              void* d_out, int out_size, void* d_ws, size_t ws_size,
                              hipStream_t stream) {
  const float* x = (const float*)d_in[0];
  const float* coord = (const float*)d_in[1];
  const float* ln_g = (const float*)d_in[2];
  const float* ln_b = (const float*)d_in[3];
  const float* w_qkv = (const float*)d_in[4];
  const float* w_out = (const float*)d_in[5];
  const float* b_out = (const float*)d_in[6];
  float* out = (float*)d_out;

  float* ws = (float*)d_ws;
  float* qb = ws;                          // BN*D floats; later reused as attn out
  float* kb = ws + (size_t)BN * D;         // BN*D
  float* vb = ws + (size_t)2 * BN * D;     // BN*D
  float* st = ws + (size_t)3 * BN * D;     // BN*2 (mu, rsqrt)

  hipLaunchKernelGGL(ln_stats_kernel, dim3(BN), dim3(256), 0, stream, x, st);
  hipLaunchKernelGGL(qkv_kernel, dim3(BN / 64, 12), dim3(256), 0, stream,
                     x, st, ln_g, ln_b, w_qkv, coord, qb, kb, vb);
  hipLaunchKernelGGL(attn_kernel, dim3(N / 64, B), dim3(256), 0, stream,
                     qb, kb, vb, qb);
  hipLaunchKernelGGL(proj_kernel, dim3(BN / 64, 4), dim3(256), 0, stream,
                     qb, w_out, b_out, out);
}

// Round 2
// 1033.250 us; speedup vs baseline: 1.7406x; 1.7406x over previous
//
#include <hip/hip_runtime.h>
#include <hip/hip_bf16.h>
#include <math.h>

constexpr int B = 4, N = 4096, D = 256;
constexpr int BN = B * N;
constexpr float EPS = 1e-5f;
// softmax scale (D^-0.5 = 1/16) * log2(e), folded into q at bf16-cast time
constexpr float QSC = 0.0625f * 1.44269504088896340736f;

constexpr int ASTR = 36;
constexpr int BSTR = 72;

typedef __attribute__((ext_vector_type(8))) short bf16x8;
typedef __attribute__((ext_vector_type(4))) float f32x4;

__device__ inline f32x4 mfma16(bf16x8 a, bf16x8 b, f32x4 c) {
  return __builtin_amdgcn_mfma_f32_16x16x32_bf16(a, b, c, 0, 0, 0);
}
__device__ inline ushort f2bf(float x) {
  __hip_bfloat16 h = __float2bfloat16(x);
  return *(ushort*)&h;
}
__device__ inline float bf2f(ushort u) {
  __hip_bfloat16 h;
  *(ushort*)&h = u;
  return __bfloat162float(h);
}

// ---------------- LayerNorm row statistics ----------------
__global__ __launch_bounds__(256) void ln_stats_kernel(
    const float* __restrict__ x, float* __restrict__ st) {
  const int row = blockIdx.x;
  const int t = threadIdx.x;
  const float v = x[(size_t)row * D + t];
  float s = v, ss = v * v;
#pragma unroll
  for (int o = 32; o > 0; o >>= 1) {
    s += __shfl_down(s, o);
    ss += __shfl_down(ss, o);
  }
  __shared__ float red[8];
  if ((t & 63) == 0) {
    red[t >> 6] = s;
    red[(t >> 6) + 4] = ss;
  }
  __syncthreads();
  if (t == 0) {
    s = red[0] + red[1] + red[2] + red[3];
    ss = red[4] + red[5] + red[6] + red[7];
    const float mu = s * (1.0f / D);
    const float var = ss * (1.0f / D) - mu * mu;
    st[2 * row] = mu;
    st[2 * row + 1] = rsqrtf(var + EPS);
  }
}

// ---------------- fused LN + QKV GEMM + coord bias + bf16 hi/lo split ------
// q planes get coord added then scaled by QSC; k planes get coord added;
// v written TRANSPOSED [b][d][n] single bf16 plane.
__global__ __launch_bounds__(256) void qkv_kernel(
    const float* __restrict__ x, const float* __restrict__ st,
    const float* __restrict__ g, const float* __restrict__ bta,
    const float* __restrict__ w, const float* __restrict__ coord,
    ushort* __restrict__ qh, ushort* __restrict__ ql,
    ushort* __restrict__ kh, ushort* __restrict__ kl,
    ushort* __restrict__ vt) {
  __shared__ float As[64 * ASTR];
  __shared__ float Bs[32 * BSTR];
  const int t = threadIdx.x;
  const int tr = t >> 4, tc = t & 15;
  const int r0 = blockIdx.x * 64;
  const int c0 = blockIdx.y * 64;  // within [0,768)
  float acc[4][4] = {};
  const int lr = t >> 3, lc = (t & 7) * 4;
  const int br = t >> 4, bc4 = (t & 15) * 4;

  const float mu0 = st[2 * (r0 + lr)], rg0 = st[2 * (r0 + lr) + 1];
  const float mu1 = st[2 * (r0 + lr + 32)], rg1 = st[2 * (r0 + lr + 32) + 1];

  for (int kc = 0; kc < D; kc += 32) {
    __syncthreads();
    {
      float4 xa = *(const float4*)&x[(size_t)(r0 + lr) * D + kc + lc];
      float4 xb = *(const float4*)&x[(size_t)(r0 + lr + 32) * D + kc + lc];
      const float4 gv = *(const float4*)&g[kc + lc];
      const float4 bv = *(const float4*)&bta[kc + lc];
      float4 a0, a1;
      a0.x = (xa.x - mu0) * rg0 * gv.x + bv.x;
      a0.y = (xa.y - mu0) * rg0 * gv.y + bv.y;
      a0.z = (xa.z - mu0) * rg0 * gv.z + bv.z;
      a0.w = (xa.w - mu0) * rg0 * gv.w + bv.w;
      a1.x = (xb.x - mu1) * rg1 * gv.x + bv.x;
      a1.y = (xb.y - mu1) * rg1 * gv.y + bv.y;
      a1.z = (xb.z - mu1) * rg1 * gv.z + bv.z;
      a1.w = (xb.w - mu1) * rg1 * gv.w + bv.w;
      *(float4*)&As[lr * ASTR + lc] = a0;
      *(float4*)&As[(lr + 32) * ASTR + lc] = a1;
      *(float4*)&Bs[br * BSTR + bc4] =
          *(const float4*)&w[(size_t)(kc + br) * 768 + c0 + bc4];
      *(float4*)&Bs[(br + 16) * BSTR + bc4] =
          *(const float4*)&w[(size_t)(kc + br + 16) * 768 + c0 + bc4];
    }
    __syncthreads();
#pragma unroll
    for (int kk = 0; kk < 32; kk += 4) {
      float ar[4][4];
#pragma unroll
      for (int i = 0; i < 4; ++i) {
        const float4 av = *(const float4*)&As[(tr * 4 + i) * ASTR + kk];
        ar[i][0] = av.x; ar[i][1] = av.y; ar[i][2] = av.z; ar[i][3] = av.w;
      }
#pragma unroll
      for (int dd = 0; dd < 4; ++dd) {
        const float4 bv = *(const float4*)&Bs[(kk + dd) * BSTR + tc * 4];
#pragma unroll
        for (int i = 0; i < 4; ++i) {
          acc[i][0] += ar[i][dd] * bv.x;
          acc[i][1] += ar[i][dd] * bv.y;
          acc[i][2] += ar[i][dd] * bv.z;
          acc[i][3] += ar[i][dd] * bv.w;
        }
      }
    }
  }
  const int region = c0 >> 8;  // 0:q 1:k 2:v (uniform per block)
  const int cr = (c0 & 255) + tc * 4;
  if (region < 2) {
    const float sc = (region == 0) ? QSC : 1.0f;
    ushort* hp = (region == 0) ? qh : kh;
    ushort* lp = (region == 0) ? ql : kl;
#pragma unroll
    for (int i = 0; i < 4; ++i) {
      const int row = r0 + tr * 4 + i;
      const float4 c = *(const float4*)&coord[(size_t)row * D + cr];
      float v[4];
      v[0] = (acc[i][0] + c.x) * sc;
      v[1] = (acc[i][1] + c.y) * sc;
      v[2] = (acc[i][2] + c.z) * sc;
      v[3] = (acc[i][3] + c.w) * sc;
      ushort4 h, lo;
      h.x = f2bf(v[0]); lo.x = f2bf(v[0] - bf2f(h.x));
      h.y = f2bf(v[1]); lo.y = f2bf(v[1] - bf2f(h.y));
      h.z = f2bf(v[2]); lo.z = f2bf(v[2] - bf2f(h.z));
      h.w = f2bf(v[3]); lo.w = f2bf(v[3] - bf2f(h.w));
      *(ushort4*)&hp[(size_t)row * D + cr] = h;
      *(ushort4*)&lp[(size_t)row * D + cr] = lo;
    }
  } else {
    const int bb = r0 / N;
    const int n0 = r0 - bb * N + tr * 4;
#pragma unroll
    for (int i = 0; i < 4; ++i)
#pragma unroll
      for (int c = 0; c < 4; ++c)
        vt[((size_t)bb * D + cr + c) * N + n0 + i] = f2bf(acc[i][c]);
  }
}

// ---------------- MFMA flash attention ----------------
// One wave per block, 16 q-rows. S = qh*kh + ql*kh + qh*kl (hi/lo split for
// fp32-level score accuracy). P bf16 staged in LDS; V read pre-transposed.
__global__ __launch_bounds__(64) void attn_kernel(
    const ushort* __restrict__ qh, const ushort* __restrict__ ql,
    const ushort* __restrict__ kh, const ushort* __restrict__ kl,
    const ushort* __restrict__ vt, ushort* __restrict__ ao) {
  __shared__ ushort ps[16 * 72];
  const int l = threadIdx.x;
  const int lrow = l & 15;
  const int lk8 = (l >> 4) * 8;
  const int rg = (l >> 4) * 4;  // C-tile row group base
  const int b = blockIdx.y;
  const int q0 = blockIdx.x * 16;

  const size_t qoff = ((size_t)b * N + q0 + lrow) * D + lk8;
  bf16x8 qhf[8], qlf[8];
#pragma unroll
  for (int dc = 0; dc < 8; ++dc) {
    qhf[dc] = *(const bf16x8*)(qh + qoff + dc * 32);
    qlf[dc] = *(const bf16x8*)(ql + qoff + dc * 32);
  }

  const f32x4 zf = {0.f, 0.f, 0.f, 0.f};
  float m[4], lsum[4];
  f32x4 o[16];
#pragma unroll
  for (int i = 0; i < 4; ++i) { m[i] = -1e30f; lsum[i] = 0.f; }
#pragma unroll
  for (int nt = 0; nt < 16; ++nt) o[nt] = zf;

  const ushort* khb = kh + (size_t)b * N * D;
  const ushort* klb = kl + (size_t)b * N * D;
  const ushort* vtb = vt + (size_t)b * D * N;

  for (int k0 = 0; k0 < N; k0 += 64) {
    // ---- S tile: 16 q-rows x 64 keys ----
    f32x4 acc[4] = {zf, zf, zf, zf};
#pragma unroll
    for (int dc = 0; dc < 8; ++dc) {
#pragma unroll
      for (int kt = 0; kt < 4; ++kt) {
        const size_t koff = (size_t)(k0 + kt * 16 + lrow) * D + dc * 32 + lk8;
        const bf16x8 kfh = *(const bf16x8*)(khb + koff);
        const bf16x8 kfl = *(const bf16x8*)(klb + koff);
        acc[kt] = mfma16(qhf[dc], kfh, acc[kt]);
        acc[kt] = mfma16(qlf[dc], kfh, acc[kt]);
        acc[kt] = mfma16(qhf[dc], kfl, acc[kt]);
      }
    }
    // ---- online softmax (base-2 domain; scale folded into q) ----
    float rm[4];
#pragma unroll
    for (int i = 0; i < 4; ++i) {
      rm[i] = fmaxf(fmaxf(acc[0][i], acc[1][i]), fmaxf(acc[2][i], acc[3][i]));
#pragma unroll
      for (int off = 1; off < 16; off <<= 1)
        rm[i] = fmaxf(rm[i], __shfl_xor(rm[i], off));
    }
    const int nogrow = (rm[0] <= m[0]) & (rm[1] <= m[1]) &
                       (rm[2] <= m[2]) & (rm[3] <= m[3]);
    if (!__all(nogrow)) {
#pragma unroll
      for (int i = 0; i < 4; ++i) {
        const float mn = fmaxf(m[i], rm[i]);
        const float f = exp2f(m[i] - mn);
        m[i] = mn;
        lsum[i] *= f;
#pragma unroll
        for (int nt = 0; nt < 16; ++nt) o[nt][i] *= f;
      }
    }
    float rs[4] = {0.f, 0.f, 0.f, 0.f};
#pragma unroll
    for (int kt = 0; kt < 4; ++kt) {
#pragma unroll
      for (int i = 0; i < 4; ++i) {
        const float p = exp2f(acc[kt][i] - m[i]);
        rs[i] += p;
        ps[(rg + i) * 72 + kt * 16 + lrow] = f2bf(p);
      }
    }
#pragma unroll
    for (int i = 0; i < 4; ++i) {
#pragma unroll
      for (int off = 1; off < 16; off <<= 1) rs[i] += __shfl_xor(rs[i], off);
      lsum[i] += rs[i];
    }
    // make P LDS writes visible to all lanes' reads (single-wave block)
    asm volatile("s_waitcnt lgkmcnt(0)" ::: "memory");
    // ---- O += P V ----
#pragma unroll
    for (int kk = 0; kk < 2; ++kk) {
      const bf16x8 pf = *(const bf16x8*)&ps[lrow * 72 + kk * 32 + lk8];
#pragma unroll
      for (int nt = 0; nt < 16; ++nt) {
        const bf16x8 vf = *(const bf16x8*)(
            vtb + (size_t)(nt * 16 + lrow) * N + k0 + kk * 32 + lk8);
        o[nt] = mfma16(pf, vf, o[nt]);
      }
    }
  }
  // ---- epilogue: normalize, write bf16 ----
  float inv[4];
#pragma unroll
  for (int i = 0; i < 4; ++i) inv[i] = 1.0f / lsum[i];
  ushort* aop = ao + ((size_t)b * N + q0) * D;
#pragma unroll
  for (int nt = 0; nt < 16; ++nt) {
#pragma unroll
    for (int i = 0; i < 4; ++i)
      aop[(size_t)(rg + i) * D + nt * 16 + lrow] = f2bf(o[nt][i] * inv[i]);
  }
}

// ---------------- output projection + bias (A is bf16) ----------------
__global__ __launch_bounds__(256) void proj_kernel(
    const ushort* __restrict__ a, const float* __restrict__ w,
    const float* __restrict__ bias, float* __restrict__ out) {
  __shared__ float As[64 * ASTR];
  __shared__ float Bs[32 * BSTR];
  const int t = threadIdx.x;
  const int tr = t >> 4, tc = t & 15;
  const int r0 = blockIdx.x * 64;
  const int c0 = blockIdx.y * 64;
  float acc[4][4] = {};
  const int ar = t >> 2, ac = (t & 3) * 8;
  const int br = t >> 4, bc4 = (t & 15) * 4;
  for (int kc = 0; kc < D; kc += 32) {
    __syncthreads();
    {
      const ushort4 u0 = *(const ushort4*)&a[(size_t)(r0 + ar) * D + kc + ac];
      const ushort4 u1 = *(const ushort4*)&a[(size_t)(r0 + ar) * D + kc + ac + 4];
      float4 f0, f1;
      f0.x = bf2f(u0.x); f0.y = bf2f(u0.y); f0.z = bf2f(u0.z); f0.w = bf2f(u0.w);
      f1.x = bf2f(u1.x); f1.y = bf2f(u1.y); f1.z = bf2f(u1.z); f1.w = bf2f(u1.w);
      *(float4*)&As[ar * ASTR + ac] = f0;
      *(float4*)&As[ar * ASTR + ac + 4] = f1;
      *(float4*)&Bs[br * BSTR + bc4] =
          *(const float4*)&w[(size_t)(kc + br) * D + c0 + bc4];
      *(float4*)&Bs[(br + 16) * BSTR + bc4] =
          *(const float4*)&w[(size_t)(kc + br + 16) * D + c0 + bc4];
    }
    __syncthreads();
#pragma unroll
    for (int kk = 0; kk < 32; kk += 4) {
      float arr[4][4];
#pragma unroll
      for (int i = 0; i < 4; ++i) {
        const float4 av = *(const float4*)&As[(tr * 4 + i) * ASTR + kk];
        arr[i][0] = av.x; arr[i][1] = av.y; arr[i][2] = av.z; arr[i][3] = av.w;
      }
#pragma unroll
      for (int dd = 0; dd < 4; ++dd) {
        const float4 bv = *(const float4*)&Bs[(kk + dd) * BSTR + tc * 4];
#pragma unroll
        for (int i = 0; i < 4; ++i) {
          acc[i][0] += arr[i][dd] * bv.x;
          acc[i][1] += arr[i][dd] * bv.y;
          acc[i][2] += arr[i][dd] * bv.z;
          acc[i][3] += arr[i][dd] * bv.w;
        }
      }
    }
  }
  const int cg = c0 + tc * 4;
  const float4 bv = *(const float4*)&bias[cg];
#pragma unroll
  for (int i = 0; i < 4; ++i) {
    const int row = r0 + tr * 4 + i;
    float4 r;
    r.x = acc[i][0] + bv.x;
    r.y = acc[i][1] + bv.y;
    r.z = acc[i][2] + bv.z;
    r.w = acc[i][3] + bv.w;
    *(float4*)&out[(size_t)row * D + cg] = r;
  }
}

extern "C" void kernel_launch(void* const* d_in, const int* in_sizes, int n_in,
                              void* d_out, int out_size, void* d_ws, size_t ws_size,
                              hipStream_t stream) {
  const float* x = (const float*)d_in[0];
  const float* coord = (const float*)d_in[1];
  const float* ln_g = (const float*)d_in[2];
  const float* ln_b = (const float*)d_in[3];
  const float* w_qkv = (const float*)d_in[4];
  const float* w_out = (const float*)d_in[5];
  const float* b_out = (const float*)d_in[6];
  float* out = (float*)d_out;

  const size_t P = (size_t)BN * D;
  ushort* qh = (ushort*)d_ws;
  ushort* ql = qh + P;
  ushort* kh = ql + P;
  ushort* kl = kh + P;
  ushort* vt = kl + P;
  ushort* ao = vt + P;
  float* st = (float*)(ao + P);

  hipLaunchKernelGGL(ln_stats_kernel, dim3(BN), dim3(256), 0, stream, x, st);
  hipLaunchKernelGGL(qkv_kernel, dim3(BN / 64, 12), dim3(256), 0, stream,
                     x, st, ln_g, ln_b, w_qkv, coord, qh, ql, kh, kl, vt);
  hipLaunchKernelGGL(attn_kernel, dim3(N / 16, B), dim3(64), 0, stream,
                     qh, ql, kh, kl, vt, ao);
  hipLaunchKernelGGL(proj_kernel, dim3(BN / 64, 4), dim3(256), 0, stream,
                     ao, w_out, b_out, out);
}

// Round 3
// 357.345 us; speedup vs baseline: 5.0329x; 2.8915x over previous
//
#include <hip/hip_runtime.h>
#include <hip/hip_fp16.h>
#include <math.h>

constexpr int B = 4, N = 4096, D = 256;
constexpr int BN = B * N;
constexpr float EPS = 1e-5f;
// softmax scale (D^-0.5 = 1/16) * log2(e), folded into q at f16-cast time
constexpr float QSC2 = 0.0625f * 1.44269504088896340736f;

constexpr int SPLIT = 2;           // KV splits
constexpr int KB = 64;             // keys per tile
constexpr int NT = (N / SPLIT) / KB;  // 32 tiles per block

constexpr int ASTR = 36;
constexpr int BSTR = 72;

typedef __attribute__((ext_vector_type(8))) _Float16 f16x8;
typedef __attribute__((ext_vector_type(4))) float f32x4;

__device__ inline f32x4 mfma_f16(f16x8 a, f16x8 b, f32x4 c) {
  return __builtin_amdgcn_mfma_f32_16x16x32_f16(a, b, c, 0, 0, 0);
}
__device__ inline ushort f2h(float x) {
  __half h = __float2half(x);
  return *(ushort*)&h;
}
__device__ inline float h2f(ushort u) {
  __half h;
  *(ushort*)&h = u;
  return __half2float(h);
}
// async global->LDS, 16B per lane; lds dest = uniform base + lane*16 (HW rule)
__device__ inline void gload16(const ushort* g, ushort* l) {
  __builtin_amdgcn_global_load_lds(
      (const __attribute__((address_space(1))) void*)g,
      (__attribute__((address_space(3))) void*)l, 16, 0, 0);
}

// ---------------- LayerNorm row statistics ----------------
__global__ __launch_bounds__(256) void ln_stats_kernel(
    const float* __restrict__ x, float* __restrict__ st) {
  const int row = blockIdx.x;
  const int t = threadIdx.x;
  const float v = x[(size_t)row * D + t];
  float s = v, ss = v * v;
#pragma unroll
  for (int o = 32; o > 0; o >>= 1) {
    s += __shfl_down(s, o);
    ss += __shfl_down(ss, o);
  }
  __shared__ float red[8];
  if ((t & 63) == 0) {
    red[t >> 6] = s;
    red[(t >> 6) + 4] = ss;
  }
  __syncthreads();
  if (t == 0) {
    s = red[0] + red[1] + red[2] + red[3];
    ss = red[4] + red[5] + red[6] + red[7];
    const float mu = s * (1.0f / D);
    const float var = ss * (1.0f / D) - mu * mu;
    st[2 * row] = mu;
    st[2 * row + 1] = rsqrtf(var + EPS);
  }
}

// ---------------- fused LN + QKV GEMM + coord bias, f16 outputs ------------
// q: (acc+coord)*QSC2 -> f16 [b*n][d]; k: (acc+coord) -> f16 [b*n][d];
// v: f16 TRANSPOSED [b][d][n].
__global__ __launch_bounds__(256) void qkv_kernel(
    const float* __restrict__ x, const float* __restrict__ st,
    const float* __restrict__ g, const float* __restrict__ bta,
    const float* __restrict__ w, const float* __restrict__ coord,
    ushort* __restrict__ qfp, ushort* __restrict__ kfp,
    ushort* __restrict__ vtp) {
  __shared__ float As[64 * ASTR];
  __shared__ float Bs[32 * BSTR];
  const int t = threadIdx.x;
  const int tr = t >> 4, tc = t & 15;
  const int r0 = blockIdx.x * 64;
  const int c0 = blockIdx.y * 64;  // within [0,768)
  float acc[4][4] = {};
  const int lr = t >> 3, lc = (t & 7) * 4;
  const int br = t >> 4, bc4 = (t & 15) * 4;

  const float mu0 = st[2 * (r0 + lr)], rg0 = st[2 * (r0 + lr) + 1];
  const float mu1 = st[2 * (r0 + lr + 32)], rg1 = st[2 * (r0 + lr + 32) + 1];

  for (int kc = 0; kc < D; kc += 32) {
    __syncthreads();
    {
      float4 xa = *(const float4*)&x[(size_t)(r0 + lr) * D + kc + lc];
      float4 xb = *(const float4*)&x[(size_t)(r0 + lr + 32) * D + kc + lc];
      const float4 gv = *(const float4*)&g[kc + lc];
      const float4 bv = *(const float4*)&bta[kc + lc];
      float4 a0, a1;
      a0.x = (xa.x - mu0) * rg0 * gv.x + bv.x;
      a0.y = (xa.y - mu0) * rg0 * gv.y + bv.y;
      a0.z = (xa.z - mu0) * rg0 * gv.z + bv.z;
      a0.w = (xa.w - mu0) * rg0 * gv.w + bv.w;
      a1.x = (xb.x - mu1) * rg1 * gv.x + bv.x;
      a1.y = (xb.y - mu1) * rg1 * gv.y + bv.y;
      a1.z = (xb.z - mu1) * rg1 * gv.z + bv.z;
      a1.w = (xb.w - mu1) * rg1 * gv.w + bv.w;
      *(float4*)&As[lr * ASTR + lc] = a0;
      *(float4*)&As[(lr + 32) * ASTR + lc] = a1;
      *(float4*)&Bs[br * BSTR + bc4] =
          *(const float4*)&w[(size_t)(kc + br) * 768 + c0 + bc4];
      *(float4*)&Bs[(br + 16) * BSTR + bc4] =
          *(const float4*)&w[(size_t)(kc + br + 16) * 768 + c0 + bc4];
    }
    __syncthreads();
#pragma unroll
    for (int kk = 0; kk < 32; kk += 4) {
      float ar[4][4];
#pragma unroll
      for (int i = 0; i < 4; ++i) {
        const float4 av = *(const float4*)&As[(tr * 4 + i) * ASTR + kk];
        ar[i][0] = av.x; ar[i][1] = av.y; ar[i][2] = av.z; ar[i][3] = av.w;
      }
#pragma unroll
      for (int dd = 0; dd < 4; ++dd) {
        const float4 bv = *(const float4*)&Bs[(kk + dd) * BSTR + tc * 4];
#pragma unroll
        for (int i = 0; i < 4; ++i) {
          acc[i][0] += ar[i][dd] * bv.x;
          acc[i][1] += ar[i][dd] * bv.y;
          acc[i][2] += ar[i][dd] * bv.z;
          acc[i][3] += ar[i][dd] * bv.w;
        }
      }
    }
  }
  const int region = c0 >> 8;  // 0:q 1:k 2:v (uniform per block)
  const int cr = (c0 & 255) + tc * 4;
  if (region < 2) {
    const float sc = (region == 0) ? QSC2 : 1.0f;
    ushort* dp = (region == 0) ? qfp : kfp;
#pragma unroll
    for (int i = 0; i < 4; ++i) {
      const int row = r0 + tr * 4 + i;
      const float4 c = *(const float4*)&coord[(size_t)row * D + cr];
      ushort4 h;
      h.x = f2h((acc[i][0] + c.x) * sc);
      h.y = f2h((acc[i][1] + c.y) * sc);
      h.z = f2h((acc[i][2] + c.z) * sc);
      h.w = f2h((acc[i][3] + c.w) * sc);
      *(ushort4*)&dp[(size_t)row * D + cr] = h;
    }
  } else {
    const int bb = r0 / N;
    const int n0 = r0 - bb * N + tr * 4;
#pragma unroll
    for (int i = 0; i < 4; ++i)
#pragma unroll
      for (int c = 0; c < 4; ++c)
        vtp[((size_t)bb * D + cr + c) * N + n0 + i] = f2h(acc[i][c]);
  }
}

// ---------------- MFMA flash attention ----------------
// 4 waves/block, 32 q-rows per wave (QB=128), KB=64 keys/tile, KV-split=2.
// Double-buffered global_load_lds staging, counted vmcnt, raw s_barrier.
// LDS layouts are fragment-major (16 lanes read consecutive 16B): K tile
// [d8-group g=0..31][key 0..63]x8h, V tile [key8-group sl=0..7][d 0..255]x8h.
__global__ __launch_bounds__(256, 1) void attn_kernel(
    const ushort* __restrict__ qf, const ushort* __restrict__ kf,
    const ushort* __restrict__ vt, ushort* __restrict__ po0,
    ushort* __restrict__ po1, float* __restrict__ ml0,
    float* __restrict__ ml1) {
  __shared__ ushort kbuf[2][16384];  // 32KB each
  __shared__ ushort vbuf[2][16384];  // 32KB each
  __shared__ ushort ps[4][32 * 72];  // per-wave P tile, stride 72h=144B

  const int tid = threadIdx.x;
  const int w = tid >> 6, lane = tid & 63;
  const int lrow = lane & 15, lhi = lane >> 4;
  const int b = blockIdx.y, s = blockIdx.z;
  const int qw = blockIdx.x * 128 + w * 32;
  const int kbeg = s * (N / SPLIT);

  const ushort* qfb = qf + (size_t)b * N * D;
  const ushort* kfb = kf + (size_t)b * N * D;
  const ushort* vtb = vt + (size_t)b * D * N;
  ushort* pog = (s == 0) ? po0 : po1;
  float* mlg = (s == 0) ? ml0 : ml1;

  // Q fragments in registers: 2 q-subtiles x 8 d-chunks
  f16x8 qfr[2][8];
#pragma unroll
  for (int qs = 0; qs < 2; ++qs)
#pragma unroll
    for (int dc = 0; dc < 8; ++dc)
      qfr[qs][dc] = *(const f16x8*)(
          qfb + (size_t)(qw + qs * 16 + lrow) * D + dc * 32 + lhi * 8);

  f32x4 o[2][16];
  float m[2][4], lsum[2][4];
#pragma unroll
  for (int qs = 0; qs < 2; ++qs) {
#pragma unroll
    for (int i = 0; i < 4; ++i) { m[qs][i] = -1e30f; lsum[qs][i] = 0.f; }
#pragma unroll
    for (int nt = 0; nt < 16; ++nt) o[qs][nt] = f32x4{0.f, 0.f, 0.f, 0.f};
  }

  // 16 issues/wave: K g = i*4+w (keys = lane); V sl = i (d = w*64+lane)
  auto stage = [&](int bi, int k0) {
#pragma unroll
    for (int i = 0; i < 8; ++i) {
      const int g = i * 4 + w;
      gload16(kfb + (size_t)(k0 + lane) * D + g * 8, &kbuf[bi][g * 512]);
    }
#pragma unroll
    for (int i = 0; i < 8; ++i) {
      gload16(vtb + (size_t)(w * 64 + lane) * N + k0 + i * 8,
              &vbuf[bi][i * 2048 + w * 512]);
    }
  };

  stage(0, kbeg);

  for (int t = 0; t < NT; ++t) {
    const int cur = t & 1;
    if (t + 1 < NT) {
      stage(cur ^ 1, kbeg + (t + 1) * KB);
      asm volatile("s_waitcnt vmcnt(16)" ::: "memory");
    } else {
      asm volatile("s_waitcnt vmcnt(0)" ::: "memory");
    }
    __builtin_amdgcn_sched_barrier(0);
    __builtin_amdgcn_s_barrier();
    __builtin_amdgcn_sched_barrier(0);

    // ---- S = Q K^T : 2 q-subtiles x 4 key-subtiles ----
    f32x4 acc[2][4];
#pragma unroll
    for (int qs = 0; qs < 2; ++qs)
#pragma unroll
      for (int kt = 0; kt < 4; ++kt) acc[qs][kt] = f32x4{0.f, 0.f, 0.f, 0.f};
#pragma unroll
    for (int dc = 0; dc < 8; ++dc)
#pragma unroll
      for (int kt = 0; kt < 4; ++kt) {
        const f16x8 kv = *(const f16x8*)&kbuf[cur][((dc * 4 + lhi) * 64 +
                                                    kt * 16 + lrow) * 8];
        acc[0][kt] = mfma_f16(qfr[0][dc], kv, acc[0][kt]);
        acc[1][kt] = mfma_f16(qfr[1][dc], kv, acc[1][kt]);
      }

    // ---- online softmax (base-2 domain) ----
    float rm[2][4];
#pragma unroll
    for (int qs = 0; qs < 2; ++qs)
#pragma unroll
      for (int i = 0; i < 4; ++i) {
        float v = fmaxf(fmaxf(acc[qs][0][i], acc[qs][1][i]),
                        fmaxf(acc[qs][2][i], acc[qs][3][i]));
#pragma unroll
        for (int off = 1; off < 16; off <<= 1) v = fmaxf(v, __shfl_xor(v, off));
        rm[qs][i] = v;
      }
    bool grow = false;
#pragma unroll
    for (int qs = 0; qs < 2; ++qs)
#pragma unroll
      for (int i = 0; i < 4; ++i) grow |= (rm[qs][i] > m[qs][i]);
    if (__any(grow)) {
#pragma unroll
      for (int qs = 0; qs < 2; ++qs)
#pragma unroll
        for (int i = 0; i < 4; ++i) {
          const float mn = fmaxf(m[qs][i], rm[qs][i]);
          const float f = exp2f(m[qs][i] - mn);
          m[qs][i] = mn;
          lsum[qs][i] *= f;
#pragma unroll
          for (int nt = 0; nt < 16; ++nt) o[qs][nt][i] *= f;
        }
    }
    float rs[2][4] = {};
#pragma unroll
    for (int qs = 0; qs < 2; ++qs)
#pragma unroll
      for (int kt = 0; kt < 4; ++kt)
#pragma unroll
        for (int i = 0; i < 4; ++i) {
          const float p = exp2f(acc[qs][kt][i] - m[qs][i]);
          rs[qs][i] += p;
          ps[w][(qs * 16 + lhi * 4 + i) * 72 + kt * 16 + lrow] = f2h(p);
        }
#pragma unroll
    for (int qs = 0; qs < 2; ++qs)
#pragma unroll
      for (int i = 0; i < 4; ++i) {
        float v = rs[qs][i];
#pragma unroll
        for (int off = 1; off < 16; off <<= 1) v += __shfl_xor(v, off);
        lsum[qs][i] += v;
      }

    // ---- O += P V ----
#pragma unroll
    for (int kk = 0; kk < 2; ++kk) {
      const f16x8 pf0 = *(const f16x8*)&ps[w][(lrow) * 72 + kk * 32 + lhi * 8];
      const f16x8 pf1 =
          *(const f16x8*)&ps[w][(16 + lrow) * 72 + kk * 32 + lhi * 8];
#pragma unroll
      for (int nt = 0; nt < 16; ++nt) {
        const f16x8 vv = *(const f16x8*)&vbuf[cur][((kk * 4 + lhi) * 256 +
                                                    nt * 16 + lrow) * 8];
        o[0][nt] = mfma_f16(pf0, vv, o[0][nt]);
        o[1][nt] = mfma_f16(pf1, vv, o[1][nt]);
      }
    }
    __builtin_amdgcn_s_barrier();
    __builtin_amdgcn_sched_barrier(0);
  }

  // ---- epilogue: normalized partial O (f16) + (m, l) per row ----
  float inv[2][4];
#pragma unroll
  for (int qs = 0; qs < 2; ++qs)
#pragma unroll
    for (int i = 0; i < 4; ++i) inv[qs][i] = 1.0f / lsum[qs][i];
#pragma unroll
  for (int qs = 0; qs < 2; ++qs)
#pragma unroll
    for (int nt = 0; nt < 16; ++nt)
#pragma unroll
      for (int i = 0; i < 4; ++i)
        pog[((size_t)b * N + qw + qs * 16 + lhi * 4 + i) * D + nt * 16 + lrow] =
            f2h(o[qs][nt][i] * inv[qs][i]);
  if (lrow == 0) {
#pragma unroll
    for (int qs = 0; qs < 2; ++qs)
#pragma unroll
      for (int i = 0; i < 4; ++i) {
        const size_t r = (size_t)b * N + qw + qs * 16 + lhi * 4 + i;
        mlg[r * 2] = m[qs][i];
        mlg[r * 2 + 1] = lsum[qs][i];
      }
  }
}

// ---------------- merge the 2 KV-split partials ----------------
__global__ __launch_bounds__(256) void merge_kernel(
    const ushort* __restrict__ po0, const ushort* __restrict__ po1,
    const float* __restrict__ ml0, const float* __restrict__ ml1,
    ushort* __restrict__ ao /* aliases po0 */) {
  const int t = threadIdx.x;
  const int row = blockIdx.x * 8 + (t >> 5);
  const int d0 = (t & 31) * 8;
  const float m0 = ml0[row * 2], l0 = ml0[row * 2 + 1];
  const float m1 = ml1[row * 2], l1 = ml1[row * 2 + 1];
  const float mm = fmaxf(m0, m1);
  const float w0 = exp2f(m0 - mm) * l0, w1 = exp2f(m1 - mm) * l1;
  const float inv = 1.0f / (w0 + w1);
  const float a0 = w0 * inv, a1 = w1 * inv;
  const size_t off = (size_t)row * D + d0;
  const f16x8 p0 = *(const f16x8*)(po0 + off);
  const f16x8 p1 = *(const f16x8*)(po1 + off);
  f16x8 r;
#pragma unroll
  for (int j = 0; j < 8; ++j)
    r[j] = (_Float16)(a0 * (float)p0[j] + a1 * (float)p1[j]);
  *(f16x8*)(ao + off) = r;
}

// ---------------- output projection + bias (A is f16) ----------------
__global__ __launch_bounds__(256) void proj_kernel(
    const ushort* __restrict__ a, const float* __restrict__ w,
    const float* __restrict__ bias, float* __restrict__ out) {
  __shared__ float As[64 * ASTR];
  __shared__ float Bs[32 * BSTR];
  const int t = threadIdx.x;
  const int tr = t >> 4, tc = t & 15;
  const int r0 = blockIdx.x * 64;
  const int c0 = blockIdx.y * 64;
  float acc[4][4] = {};
  const int ar = t >> 2, ac = (t & 3) * 8;
  const int br = t >> 4, bc4 = (t & 15) * 4;
  for (int kc = 0; kc < D; kc += 32) {
    __syncthreads();
    {
      const ushort4 u0 = *(const ushort4*)&a[(size_t)(r0 + ar) * D + kc + ac];
      const ushort4 u1 =
          *(const ushort4*)&a[(size_t)(r0 + ar) * D + kc + ac + 4];
      float4 f0, f1;
      f0.x = h2f(u0.x); f0.y = h2f(u0.y); f0.z = h2f(u0.z); f0.w = h2f(u0.w);
      f1.x = h2f(u1.x); f1.y = h2f(u1.y); f1.z = h2f(u1.z); f1.w = h2f(u1.w);
      *(float4*)&As[ar * ASTR + ac] = f0;
      *(float4*)&As[ar * ASTR + ac + 4] = f1;
      *(float4*)&Bs[br * BSTR + bc4] =
          *(const float4*)&w[(size_t)(kc + br) * D + c0 + bc4];
      *(float4*)&Bs[(br + 16) * BSTR + bc4] =
          *(const float4*)&w[(size_t)(kc + br + 16) * D + c0 + bc4];
    }
    __syncthreads();
#pragma unroll
    for (int kk = 0; kk < 32; kk += 4) {
      float arr[4][4];
#pragma unroll
      for (int i = 0; i < 4; ++i) {
        const float4 av = *(const float4*)&As[(tr * 4 + i) * ASTR + kk];
        arr[i][0] = av.x; arr[i][1] = av.y; arr[i][2] = av.z; arr[i][3] = av.w;
      }
#pragma unroll
      for (int dd = 0; dd < 4; ++dd) {
        const float4 bv = *(const float4*)&Bs[(kk + dd) * BSTR + tc * 4];
#pragma unroll
        for (int i = 0; i < 4; ++i) {
          acc[i][0] += arr[i][dd] * bv.x;
          acc[i][1] += arr[i][dd] * bv.y;
          acc[i][2] += arr[i][dd] * bv.z;
          acc[i][3] += arr[i][dd] * bv.w;
        }
      }
    }
  }
  const int cg = c0 + tc * 4;
  const float4 bv = *(const float4*)&bias[cg];
#pragma unroll
  for (int i = 0; i < 4; ++i) {
    const int row = r0 + tr * 4 + i;
    float4 r;
    r.x = acc[i][0] + bv.x;
    r.y = acc[i][1] + bv.y;
    r.z = acc[i][2] + bv.z;
    r.w = acc[i][3] + bv.w;
    *(float4*)&out[(size_t)row * D + cg] = r;
  }
}

extern "C" void kernel_launch(void* const* d_in, const int* in_sizes, int n_in,
                              void* d_out, int out_size, void* d_ws, size_t ws_size,
                              hipStream_t stream) {
  const float* x = (const float*)d_in[0];
  const float* coord = (const float*)d_in[1];
  const float* ln_g = (const float*)d_in[2];
  const float* ln_b = (const float*)d_in[3];
  const float* w_qkv = (const float*)d_in[4];
  const float* w_out = (const float*)d_in[5];
  const float* b_out = (const float*)d_in[6];
  float* out = (float*)d_out;

  const size_t P = (size_t)BN * D;
  ushort* qfp = (ushort*)d_ws;
  ushort* kfp = qfp + P;
  ushort* vtp = kfp + P;
  ushort* po0 = vtp + P;   // split-0 partial; merged output aliases this
  ushort* po1 = po0 + P;
  float* ml0 = (float*)(po1 + P);
  float* ml1 = ml0 + (size_t)BN * 2;
  float* st = ml1 + (size_t)BN * 2;

  hipLaunchKernelGGL(ln_stats_kernel, dim3(BN), dim3(256), 0, stream, x, st);
  hipLaunchKernelGGL(qkv_kernel, dim3(BN / 64, 12), dim3(256), 0, stream,
                     x, st, ln_g, ln_b, w_qkv, coord, qfp, kfp, vtp);
  hipLaunchKernelGGL(attn_kernel, dim3(N / 128, B, SPLIT), dim3(256), 0,
                     stream, qfp, kfp, vtp, po0, po1, ml0, ml1);
  hipLaunchKernelGGL(merge_kernel, dim3(BN / 8), dim3(256), 0, stream,
                     po0, po1, ml0, ml1, po0);
  hipLaunchKernelGGL(proj_kernel, dim3(BN / 64, 4), dim3(256), 0, stream,
                     po0, w_out, b_out, out);
}

// Round 4
// 294.152 us; speedup vs baseline: 6.1141x; 1.2148x over previous
//
#include <hip/hip_runtime.h>
#include <hip/hip_fp16.h>
#include <math.h>

constexpr int B = 4, N = 4096, D = 256;
constexpr int BN = B * N;
constexpr float EPS = 1e-5f;
// softmax scale (D^-0.5 = 1/16) * log2(e), folded into q at f16-cast time
constexpr float QSC2 = 0.0625f * 1.44269504088896340736f;

constexpr int SPLIT = 4;              // KV splits
constexpr int KB = 32;                // keys per tile
constexpr int NT = (N / SPLIT) / KB;  // 32 tiles per block
constexpr float THR = 8.0f;           // defer-max threshold (base-2)

constexpr int ASTR = 36;
constexpr int BSTR = 72;
constexpr int PSTR = 40;  // P tile stride in halves (80B, 16B-multiple)

typedef __attribute__((ext_vector_type(8))) _Float16 f16x8;
typedef __attribute__((ext_vector_type(4))) float f32x4;

__device__ inline f32x4 mfma_f16(f16x8 a, f16x8 b, f32x4 c) {
  return __builtin_amdgcn_mfma_f32_16x16x32_f16(a, b, c, 0, 0, 0);
}
__device__ inline ushort f2h(float x) {
  __half h = __float2half(x);
  return *(ushort*)&h;
}
__device__ inline float h2f(ushort u) {
  __half h;
  *(ushort*)&h = u;
  return __half2float(h);
}
// async global->LDS, 16B per lane; lds dest = uniform base + lane*16 (HW rule)
__device__ inline void gload16(const ushort* g, ushort* l) {
  __builtin_amdgcn_global_load_lds(
      (const __attribute__((address_space(1))) void*)g,
      (__attribute__((address_space(3))) void*)l, 16, 0, 0);
}

// ---------------- LayerNorm row statistics ----------------
__global__ __launch_bounds__(256) void ln_stats_kernel(
    const float* __restrict__ x, float* __restrict__ st) {
  const int row = blockIdx.x;
  const int t = threadIdx.x;
  const float v = x[(size_t)row * D + t];
  float s = v, ss = v * v;
#pragma unroll
  for (int o = 32; o > 0; o >>= 1) {
    s += __shfl_down(s, o);
    ss += __shfl_down(ss, o);
  }
  __shared__ float red[8];
  if ((t & 63) == 0) {
    red[t >> 6] = s;
    red[(t >> 6) + 4] = ss;
  }
  __syncthreads();
  if (t == 0) {
    s = red[0] + red[1] + red[2] + red[3];
    ss = red[4] + red[5] + red[6] + red[7];
    const float mu = s * (1.0f / D);
    const float var = ss * (1.0f / D) - mu * mu;
    st[2 * row] = mu;
    st[2 * row + 1] = rsqrtf(var + EPS);
  }
}

// ---------------- fused LN + QKV GEMM + coord bias, f16 outputs ------------
__global__ __launch_bounds__(256) void qkv_kernel(
    const float* __restrict__ x, const float* __restrict__ st,
    const float* __restrict__ g, const float* __restrict__ bta,
    const float* __restrict__ w, const float* __restrict__ coord,
    ushort* __restrict__ qfp, ushort* __restrict__ kfp,
    ushort* __restrict__ vtp) {
  __shared__ float As[64 * ASTR];
  __shared__ float Bs[32 * BSTR];
  const int t = threadIdx.x;
  const int tr = t >> 4, tc = t & 15;
  const int r0 = blockIdx.x * 64;
  const int c0 = blockIdx.y * 64;  // within [0,768)
  float acc[4][4] = {};
  const int lr = t >> 3, lc = (t & 7) * 4;
  const int br = t >> 4, bc4 = (t & 15) * 4;

  const float mu0 = st[2 * (r0 + lr)], rg0 = st[2 * (r0 + lr) + 1];
  const float mu1 = st[2 * (r0 + lr + 32)], rg1 = st[2 * (r0 + lr + 32) + 1];

  for (int kc = 0; kc < D; kc += 32) {
    __syncthreads();
    {
      float4 xa = *(const float4*)&x[(size_t)(r0 + lr) * D + kc + lc];
      float4 xb = *(const float4*)&x[(size_t)(r0 + lr + 32) * D + kc + lc];
      const float4 gv = *(const float4*)&g[kc + lc];
      const float4 bv = *(const float4*)&bta[kc + lc];
      float4 a0, a1;
      a0.x = (xa.x - mu0) * rg0 * gv.x + bv.x;
      a0.y = (xa.y - mu0) * rg0 * gv.y + bv.y;
      a0.z = (xa.z - mu0) * rg0 * gv.z + bv.z;
      a0.w = (xa.w - mu0) * rg0 * gv.w + bv.w;
      a1.x = (xb.x - mu1) * rg1 * gv.x + bv.x;
      a1.y = (xb.y - mu1) * rg1 * gv.y + bv.y;
      a1.z = (xb.z - mu1) * rg1 * gv.z + bv.z;
      a1.w = (xb.w - mu1) * rg1 * gv.w + bv.w;
      *(float4*)&As[lr * ASTR + lc] = a0;
      *(float4*)&As[(lr + 32) * ASTR + lc] = a1;
      *(float4*)&Bs[br * BSTR + bc4] =
          *(const float4*)&w[(size_t)(kc + br) * 768 + c0 + bc4];
      *(float4*)&Bs[(br + 16) * BSTR + bc4] =
          *(const float4*)&w[(size_t)(kc + br + 16) * 768 + c0 + bc4];
    }
    __syncthreads();
#pragma unroll
    for (int kk = 0; kk < 32; kk += 4) {
      float ar[4][4];
#pragma unroll
      for (int i = 0; i < 4; ++i) {
        const float4 av = *(const float4*)&As[(tr * 4 + i) * ASTR + kk];
        ar[i][0] = av.x; ar[i][1] = av.y; ar[i][2] = av.z; ar[i][3] = av.w;
      }
#pragma unroll
      for (int dd = 0; dd < 4; ++dd) {
        const float4 bv = *(const float4*)&Bs[(kk + dd) * BSTR + tc * 4];
#pragma unroll
        for (int i = 0; i < 4; ++i) {
          acc[i][0] += ar[i][dd] * bv.x;
          acc[i][1] += ar[i][dd] * bv.y;
          acc[i][2] += ar[i][dd] * bv.z;
          acc[i][3] += ar[i][dd] * bv.w;
        }
      }
    }
  }
  const int region = c0 >> 8;  // 0:q 1:k 2:v (uniform per block)
  const int cr = (c0 & 255) + tc * 4;
  if (region < 2) {
    const float sc = (region == 0) ? QSC2 : 1.0f;
    ushort* dp = (region == 0) ? qfp : kfp;
#pragma unroll
    for (int i = 0; i < 4; ++i) {
      const int row = r0 + tr * 4 + i;
      const float4 c = *(const float4*)&coord[(size_t)row * D + cr];
      ushort4 h;
      h.x = f2h((acc[i][0] + c.x) * sc);
      h.y = f2h((acc[i][1] + c.y) * sc);
      h.z = f2h((acc[i][2] + c.z) * sc);
      h.w = f2h((acc[i][3] + c.w) * sc);
      *(ushort4*)&dp[(size_t)row * D + cr] = h;
    }
  } else {
    const int bb = r0 / N;
    const int n0 = r0 - bb * N + tr * 4;
#pragma unroll
    for (int i = 0; i < 4; ++i)
#pragma unroll
      for (int c = 0; c < 4; ++c)
        vtp[((size_t)bb * D + cr + c) * N + n0 + i] = f2h(acc[i][c]);
  }
}

// ---------------- MFMA flash attention ----------------
// 8 waves/block (512 thr), 32 q-rows/wave (QB=256), KB=32 keys/tile,
// SPLIT=4. One block/CU -> 2 waves/SIMD. K/V double-buffered via
// global_load_lds, counted vmcnt(4), raw s_barrier, defer-max softmax,
// per-lane partial lsum reduced only in the epilogue.
// LDS: kbuf [g=0..31][key 0..31][8h] (16KB x2), vbuf [sl=0..3][d 0..255][8h]
// (16KB x2), ps 8 x [32][PSTR] (20KB). Total 84KB.
__global__ __launch_bounds__(512, 2) void attn_kernel(
    const ushort* __restrict__ qf, const ushort* __restrict__ kf,
    const ushort* __restrict__ vt, ushort* __restrict__ pob,
    float* __restrict__ mlb) {
  __shared__ ushort kbuf[2][8192];
  __shared__ ushort vbuf[2][8192];
  __shared__ ushort ps[8][32 * PSTR];

  const int tid = threadIdx.x;
  const int w = tid >> 6, lane = tid & 63;
  const int lrow = lane & 15, lhi = lane >> 4;
  const int b = blockIdx.y, s = blockIdx.z;
  const int qw = blockIdx.x * 256 + w * 32;
  const int kbeg = s * (N / SPLIT);

  const ushort* qfb = qf + (size_t)b * N * D;
  const ushort* kfb = kf + (size_t)b * N * D;
  const ushort* vtb = vt + (size_t)b * D * N;
  ushort* pog = pob + (size_t)s * BN * D;
  float* mlg = mlb + (size_t)s * BN * 2;

  // Q fragments: 2 q-subtiles x 8 d-chunks
  f16x8 qfr[2][8];
#pragma unroll
  for (int qs = 0; qs < 2; ++qs)
#pragma unroll
    for (int dc = 0; dc < 8; ++dc)
      qfr[qs][dc] = *(const f16x8*)(
          qfb + (size_t)(qw + qs * 16 + lrow) * D + dc * 32 + lhi * 8);

  f32x4 o[2][16];
  float m[2][4], lsum[2][4];  // lsum: per-lane partial (this lane's columns)
#pragma unroll
  for (int qs = 0; qs < 2; ++qs) {
#pragma unroll
    for (int i = 0; i < 4; ++i) { m[qs][i] = -1e30f; lsum[qs][i] = 0.f; }
#pragma unroll
    for (int nt = 0; nt < 16; ++nt) o[qs][nt] = f32x4{0.f, 0.f, 0.f, 0.f};
  }

  // staging: 16 chunks of 1KB each for K and V; chunk c = i*8 + w, i in 0..1
  auto stage = [&](int bi, int k0) {
#pragma unroll
    for (int i = 0; i < 2; ++i) {
      const int c = i * 8 + w;
      // K chunk: g = c*2 + (lane>>5), key = lane&31
      gload16(kfb + (size_t)(k0 + (lane & 31)) * D + (c * 2 + (lane >> 5)) * 8,
              &kbuf[bi][c * 512]);
    }
#pragma unroll
    for (int i = 0; i < 2; ++i) {
      const int c = i * 8 + w;
      // V chunk: sl = c>>2, d = (c&3)*64 + lane
      gload16(vtb + (size_t)((c & 3) * 64 + lane) * N + k0 + (c >> 2) * 8,
              &vbuf[bi][c * 512]);
    }
  };

  stage(0, kbeg);

  for (int t = 0; t < NT; ++t) {
    const int cur = t & 1;
    if (t + 1 < NT) {
      stage(cur ^ 1, kbeg + (t + 1) * KB);
      asm volatile("s_waitcnt vmcnt(4)" ::: "memory");
    } else {
      asm volatile("s_waitcnt vmcnt(0)" ::: "memory");
    }
    __builtin_amdgcn_sched_barrier(0);
    __builtin_amdgcn_s_barrier();
    __builtin_amdgcn_sched_barrier(0);

    // ---- S = Q K^T : 2 q-subtiles x 2 key-subtiles ----
    f32x4 acc[2][2];
#pragma unroll
    for (int qs = 0; qs < 2; ++qs)
#pragma unroll
      for (int kt = 0; kt < 2; ++kt) acc[qs][kt] = f32x4{0.f, 0.f, 0.f, 0.f};
    __builtin_amdgcn_s_setprio(1);
#pragma unroll
    for (int dc = 0; dc < 8; ++dc)
#pragma unroll
      for (int kt = 0; kt < 2; ++kt) {
        const f16x8 kv = *(const f16x8*)&kbuf[cur][((dc * 4 + lhi) * 32 +
                                                    kt * 16 + lrow) * 8];
        acc[0][kt] = mfma_f16(qfr[0][dc], kv, acc[0][kt]);
        acc[1][kt] = mfma_f16(qfr[1][dc], kv, acc[1][kt]);
      }
    __builtin_amdgcn_s_setprio(0);

    // ---- online softmax, defer-max (THR in base-2) ----
    float rm[2][4];
    bool need = false;
#pragma unroll
    for (int qs = 0; qs < 2; ++qs)
#pragma unroll
      for (int i = 0; i < 4; ++i) {
        float v = fmaxf(acc[qs][0][i], acc[qs][1][i]);
#pragma unroll
        for (int off = 1; off < 16; off <<= 1) v = fmaxf(v, __shfl_xor(v, off));
        rm[qs][i] = v;
        need |= (v > m[qs][i] + THR);
      }
    if (__any(need)) {
#pragma unroll
      for (int qs = 0; qs < 2; ++qs)
#pragma unroll
        for (int i = 0; i < 4; ++i) {
          const float mn = fmaxf(m[qs][i], rm[qs][i]);
          const float f = exp2f(m[qs][i] - mn);
          m[qs][i] = mn;
          lsum[qs][i] *= f;
#pragma unroll
          for (int nt = 0; nt < 16; ++nt) o[qs][nt][i] *= f;
        }
    }
#pragma unroll
    for (int qs = 0; qs < 2; ++qs)
#pragma unroll
      for (int kt = 0; kt < 2; ++kt)
#pragma unroll
        for (int i = 0; i < 4; ++i) {
          const float p = exp2f(acc[qs][kt][i] - m[qs][i]);
          lsum[qs][i] += p;
          ps[w][(qs * 16 + lhi * 4 + i) * PSTR + kt * 16 + lrow] = f2h(p);
        }
    asm volatile("s_waitcnt lgkmcnt(0)" ::: "memory");
    __builtin_amdgcn_sched_barrier(0);

    // ---- O += P V (single K=32 step) ----
    const f16x8 pf0 = *(const f16x8*)&ps[w][lrow * PSTR + lhi * 8];
    const f16x8 pf1 = *(const f16x8*)&ps[w][(16 + lrow) * PSTR + lhi * 8];
    __builtin_amdgcn_s_setprio(1);
#pragma unroll
    for (int nt = 0; nt < 16; ++nt) {
      const f16x8 vv =
          *(const f16x8*)&vbuf[cur][lhi * 2048 + (nt * 16 + lrow) * 8];
      o[0][nt] = mfma_f16(pf0, vv, o[0][nt]);
      o[1][nt] = mfma_f16(pf1, vv, o[1][nt]);
    }
    __builtin_amdgcn_s_setprio(0);
    __builtin_amdgcn_s_barrier();
    __builtin_amdgcn_sched_barrier(0);
  }

  // ---- epilogue: reduce lsum across the 16 lanes of each row ----
#pragma unroll
  for (int qs = 0; qs < 2; ++qs)
#pragma unroll
    for (int i = 0; i < 4; ++i) {
      float v = lsum[qs][i];
#pragma unroll
      for (int off = 1; off < 16; off <<= 1) v += __shfl_xor(v, off);
      lsum[qs][i] = v;
    }
  float inv[2][4];
#pragma unroll
  for (int qs = 0; qs < 2; ++qs)
#pragma unroll
    for (int i = 0; i < 4; ++i) inv[qs][i] = 1.0f / lsum[qs][i];
#pragma unroll
  for (int qs = 0; qs < 2; ++qs)
#pragma unroll
    for (int nt = 0; nt < 16; ++nt)
#pragma unroll
      for (int i = 0; i < 4; ++i)
        pog[((size_t)b * N + qw + qs * 16 + lhi * 4 + i) * D + nt * 16 + lrow] =
            f2h(o[qs][nt][i] * inv[qs][i]);
  if (lrow == 0) {
#pragma unroll
    for (int qs = 0; qs < 2; ++qs)
#pragma unroll
      for (int i = 0; i < 4; ++i) {
        const size_t r = (size_t)b * N + qw + qs * 16 + lhi * 4 + i;
        mlg[r * 2] = m[qs][i];
        mlg[r * 2 + 1] = lsum[qs][i];
      }
  }
}

// ---------------- merge the 4 KV-split partials ----------------
__global__ __launch_bounds__(256) void merge_kernel(
    const ushort* __restrict__ pob, const float* __restrict__ mlb,
    ushort* __restrict__ ao /* aliases split-0 partial */) {
  const int t = threadIdx.x;
  const int row = blockIdx.x * 8 + (t >> 5);
  const int d0 = (t & 31) * 8;
  float mv[SPLIT], lv[SPLIT];
  float mm = -1e30f;
#pragma unroll
  for (int s = 0; s < SPLIT; ++s) {
    mv[s] = mlb[(size_t)s * BN * 2 + row * 2];
    lv[s] = mlb[(size_t)s * BN * 2 + row * 2 + 1];
    mm = fmaxf(mm, mv[s]);
  }
  float wsum = 0.f, a[SPLIT];
#pragma unroll
  for (int s = 0; s < SPLIT; ++s) {
    a[s] = exp2f(mv[s] - mm) * lv[s];
    wsum += a[s];
  }
  const float invw = 1.0f / wsum;
  const size_t off = (size_t)row * D + d0;
  float r[8] = {};
#pragma unroll
  for (int s = 0; s < SPLIT; ++s) {
    const f16x8 p = *(const f16x8*)(pob + (size_t)s * BN * D + off);
    const float c = a[s] * invw;
#pragma unroll
    for (int j = 0; j < 8; ++j) r[j] += c * (float)p[j];
  }
  f16x8 res;
#pragma unroll
  for (int j = 0; j < 8; ++j) res[j] = (_Float16)r[j];
  *(f16x8*)(ao + off) = res;
}

// ---------------- output projection + bias (A is f16) ----------------
__global__ __launch_bounds__(256) void proj_kernel(
    const ushort* __restrict__ a, const float* __restrict__ w,
    const float* __restrict__ bias, float* __restrict__ out) {
  __shared__ float As[64 * ASTR];
  __shared__ float Bs[32 * BSTR];
  const int t = threadIdx.x;
  const int tr = t >> 4, tc = t & 15;
  const int r0 = blockIdx.x * 64;
  const int c0 = blockIdx.y * 64;
  float acc[4][4] = {};
  const int ar = t >> 2, ac = (t & 3) * 8;
  const int br = t >> 4, bc4 = (t & 15) * 4;
  for (int kc = 0; kc < D; kc += 32) {
    __syncthreads();
    {
      const ushort4 u0 = *(const ushort4*)&a[(size_t)(r0 + ar) * D + kc + ac];
      const ushort4 u1 =
          *(const ushort4*)&a[(size_t)(r0 + ar) * D + kc + ac + 4];
      float4 f0, f1;
      f0.x = h2f(u0.x); f0.y = h2f(u0.y); f0.z = h2f(u0.z); f0.w = h2f(u0.w);
      f1.x = h2f(u1.x); f1.y = h2f(u1.y); f1.z = h2f(u1.z); f1.w = h2f(u1.w);
      *(float4*)&As[ar * ASTR + ac] = f0;
      *(float4*)&As[ar * ASTR + ac + 4] = f1;
      *(float4*)&Bs[br * BSTR + bc4] =
          *(const float4*)&w[(size_t)(kc + br) * D + c0 + bc4];
      *(float4*)&Bs[(br + 16) * BSTR + bc4] =
          *(const float4*)&w[(size_t)(kc + br + 16) * D + c0 + bc4];
    }
    __syncthreads();
#pragma unroll
    for (int kk = 0; kk < 32; kk += 4) {
      float arr[4][4];
#pragma unroll
      for (int i = 0; i < 4; ++i) {
        const float4 av = *(const float4*)&As[(tr * 4 + i) * ASTR + kk];
        arr[i][0] = av.x; arr[i][1] = av.y; arr[i][2] = av.z; arr[i][3] = av.w;
      }
#pragma unroll
      for (int dd = 0; dd < 4; ++dd) {
        const float4 bv = *(const float4*)&Bs[(kk + dd) * BSTR + tc * 4];
#pragma unroll
        for (int i = 0; i < 4; ++i) {
          acc[i][0] += arr[i][dd] * bv.x;
          acc[i][1] += arr[i][dd] * bv.y;
          acc[i][2] += arr[i][dd] * bv.z;
          acc[i][3] += arr[i][dd] * bv.w;
        }
      }
    }
  }
  const int cg = c0 + tc * 4;
  const float4 bv = *(const float4*)&bias[cg];
#pragma unroll
  for (int i = 0; i < 4; ++i) {
    const int row = r0 + tr * 4 + i;
    float4 r;
    r.x = acc[i][0] + bv.x;
    r.y = acc[i][1] + bv.y;
    r.z = acc[i][2] + bv.z;
    r.w = acc[i][3] + bv.w;
    *(float4*)&out[(size_t)row * D + cg] = r;
  }
}

extern "C" void kernel_launch(void* const* d_in, const int* in_sizes, int n_in,
                              void* d_out, int out_size, void* d_ws, size_t ws_size,
                              hipStream_t stream) {
  const float* x = (const float*)d_in[0];
  const float* coord = (const float*)d_in[1];
  const float* ln_g = (const float*)d_in[2];
  const float* ln_b = (const float*)d_in[3];
  const float* w_qkv = (const float*)d_in[4];
  const float* w_out = (const float*)d_in[5];
  const float* b_out = (const float*)d_in[6];
  float* out = (float*)d_out;

  const size_t P = (size_t)BN * D;
  ushort* qfp = (ushort*)d_ws;
  ushort* kfp = qfp + P;
  ushort* vtp = kfp + P;
  ushort* pob = vtp + P;                     // SPLIT partials; merged into s=0
  float* mlb = (float*)(pob + (size_t)SPLIT * P);
  float* st = mlb + (size_t)SPLIT * BN * 2;

  hipLaunchKernelGGL(ln_stats_kernel, dim3(BN), dim3(256), 0, stream, x, st);
  hipLaunchKernelGGL(qkv_kernel, dim3(BN / 64, 12), dim3(256), 0, stream,
                     x, st, ln_g, ln_b, w_qkv, coord, qfp, kfp, vtp);
  hipLaunchKernelGGL(attn_kernel, dim3(N / 256, B, SPLIT), dim3(512), 0,
                     stream, qfp, kfp, vtp, pob, mlb);
  hipLaunchKernelGGL(merge_kernel, dim3(BN / 8), dim3(256), 0, stream,
                     pob, mlb, pob);
  hipLaunchKernelGGL(proj_kernel, dim3(BN / 64, 4), dim3(256), 0, stream,
                     pob, w_out, b_out, out);
}